// Round 6
// baseline (836.714 us; speedup 1.0000x reference)
//
#include <hip/hip_runtime.h>
#include <hip/hip_bf16.h>

#define BATCH   16
#define NPTS    2048
#define NPOINT  512
#define CFEAT   128
#define CIN     131
#define CMID    32
#define NFPSBLK 8     // 2 batches per FPS block

typedef _Float16 half8 __attribute__((ext_vector_type(8)));
typedef float floatx4 __attribute__((ext_vector_type(4)));

// exact (non-contracted) squared distance, matching np's ((dx^2+dy^2)+dz^2)
__device__ __forceinline__ float d2_rn(float ax, float ay, float az,
                                       float bx, float by, float bz) {
  float dx = __fsub_rn(ax, bx), dy = __fsub_rn(ay, by), dz = __fsub_rn(az, bz);
  return __fadd_rn(__fadd_rn(__fmul_rn(dx, dx), __fmul_rn(dy, dy)), __fmul_rn(dz, dz));
}

// 64-lane lexicographic max of (hi,lo), result lands in lane 63.
__device__ __forceinline__ void wave_key_reduce(unsigned &hi, unsigned &lo) {
#define KSTEP(CTRL, RM, BM) {                                                     \
    unsigned h2 = (unsigned)__builtin_amdgcn_update_dpp((int)hi, (int)hi, CTRL,   \
                                                        RM, BM, false);           \
    unsigned l2 = (unsigned)__builtin_amdgcn_update_dpp((int)lo, (int)lo, CTRL,   \
                                                        RM, BM, false);           \
    bool g = (h2 > hi) || (h2 == hi && l2 > lo);                                  \
    hi = g ? h2 : hi; lo = g ? l2 : lo; }
  KSTEP(0x111, 0xf, 0xf)   // row_shr:1
  KSTEP(0x112, 0xf, 0xf)   // row_shr:2
  KSTEP(0x114, 0xf, 0xe)   // row_shr:4
  KSTEP(0x118, 0xf, 0xc)   // row_shr:8
  KSTEP(0x142, 0xa, 0xf)   // row_bcast:15
  KSTEP(0x143, 0xc, 0xf)   // row_bcast:31
#undef KSTEP
}

// blocks [0,8): FPS, 2 batches per block; blocks [8, 8+4096): transpose
__global__ __launch_bounds__(256, 1) void fps_transpose_kernel(
    const float* __restrict__ xyz, const float* __restrict__ feat,
    float* __restrict__ featT, float* __restrict__ out_xyz)
{
  int t = threadIdx.x;
  if (blockIdx.x >= NFPSBLK) {
    __shared__ float tile[32][33];
    int m  = blockIdx.x - NFPSBLK;
    int b  = m >> 8;
    int c0 = ((m >> 6) & 3) << 5;
    int n0 = (m & 63) << 5;
    int tx = t & 31, ty = t >> 5;
    const float* src = feat  + (size_t)b * CFEAT * NPTS;
    float*       dst = featT + (size_t)b * NPTS * CFEAT;
#pragma unroll
    for (int i = 0; i < 4; ++i)
      tile[ty + 8 * i][tx] = src[(size_t)(c0 + ty + 8 * i) * NPTS + n0 + tx];
    __syncthreads();
#pragma unroll
    for (int i = 0; i < 4; ++i)
      dst[(size_t)(n0 + ty + 8 * i) * CFEAT + c0 + tx] = tile[tx][ty + 8 * i];
    return;
  }
  // ---- FPS: R4's proven no-spill structure, two interleaved batches ----
  __shared__ float4 spA[NPTS], spB[NPTS];              // 64 KB
  __shared__ unsigned long long skA[2][4], skB[2][4];
  __shared__ float scA[NPOINT * 3], scB[NPOINT * 3];   // 12 KB
  int b0 = blockIdx.x * 2, b1 = b0 + 1;
  int lane = t & 63, wid = t >> 6;
  const float* xa = xyz + (size_t)b0 * NPTS * 3;
  const float* xb = xyz + (size_t)b1 * NPTS * 3;
  for (int n = t; n < NPTS; n += 256) {
    spA[n] = make_float4(xa[n * 3 + 0], xa[n * 3 + 1], xa[n * 3 + 2], 0.f);
    spB[n] = make_float4(xb[n * 3 + 0], xb[n * 3 + 1], xb[n * 3 + 2], 0.f);
  }
  __syncthreads();
  float pxA[8], pyA[8], pzA[8], dA[8];
  float pxB[8], pyB[8], pzB[8], dB[8];
#pragma unroll
  for (int i = 0; i < 8; ++i) {
    float4 qa = spA[(i << 8) + t];
    pxA[i] = qa.x; pyA[i] = qa.y; pzA[i] = qa.z; dA[i] = 1e10f;
    float4 qb = spB[(i << 8) + t];
    pxB[i] = qb.x; pyB[i] = qb.y; pzB[i] = qb.z; dB[i] = 1e10f;
  }
  float cxA, cyA, czA, cxB, cyB, czB;
  { float4 q = spA[0]; cxA = q.x; cyA = q.y; czA = q.z; }
  { float4 q = spB[0]; cxB = q.x; cyB = q.y; czB = q.z; }
  if (t == 0) {
    scA[0] = cxA; scA[1] = cyA; scA[2] = czA;
    scB[0] = cxB; scB[1] = cyB; scB[2] = czB;
  }
#pragma unroll 1
  for (int step = 1; step < NPOINT; ++step) {
    unsigned long long bkA = 0ull, bkB = 0ull;
#pragma unroll
    for (int i = 0; i < 8; ++i) {
      float ddA = d2_rn(pxA[i], pyA[i], pzA[i], cxA, cyA, czA);
      float ndA = fminf(dA[i], ddA);
      dA[i] = ndA;
      unsigned long long keyA = ((unsigned long long)__float_as_uint(ndA) << 32)
                              | (unsigned)~((i << 8) + t);
      bkA = keyA > bkA ? keyA : bkA;
      float ddB = d2_rn(pxB[i], pyB[i], pzB[i], cxB, cyB, czB);
      float ndB = fminf(dB[i], ddB);
      dB[i] = ndB;
      unsigned long long keyB = ((unsigned long long)__float_as_uint(ndB) << 32)
                              | (unsigned)~((i << 8) + t);
      bkB = keyB > bkB ? keyB : bkB;
    }
    unsigned hA = (unsigned)(bkA >> 32), lA = (unsigned)bkA;
    unsigned hB = (unsigned)(bkB >> 32), lB = (unsigned)bkB;
    wave_key_reduce(hA, lA);
    wave_key_reduce(hB, lB);
    int p = step & 1;   // double-buffered -> one barrier per step
    if (lane == 63) {
      skA[p][wid] = ((unsigned long long)hA << 32) | (unsigned long long)lA;
      skB[p][wid] = ((unsigned long long)hB << 32) | (unsigned long long)lB;
    }
    __syncthreads();
    {
      unsigned long long k0 = skA[p][0], k1 = skA[p][1];
      unsigned long long k2 = skA[p][2], k3 = skA[p][3];
      unsigned long long ka = k0 > k1 ? k0 : k1;
      unsigned long long kb = k2 > k3 ? k2 : k3;
      unsigned long long km = ka > kb ? ka : kb;
      int last = (int)(~(unsigned)(km & 0xFFFFFFFFull)) & (NPTS - 1);
      float4 q = spA[last];
      cxA = q.x; cyA = q.y; czA = q.z;
    }
    {
      unsigned long long k0 = skB[p][0], k1 = skB[p][1];
      unsigned long long k2 = skB[p][2], k3 = skB[p][3];
      unsigned long long ka = k0 > k1 ? k0 : k1;
      unsigned long long kb = k2 > k3 ? k2 : k3;
      unsigned long long km = ka > kb ? ka : kb;
      int last = (int)(~(unsigned)(km & 0xFFFFFFFFull)) & (NPTS - 1);
      float4 q = spB[last];
      cxB = q.x; cyB = q.y; czB = q.z;
    }
    if (t == 0) {
      scA[step * 3 + 0] = cxA; scA[step * 3 + 1] = cyA; scA[step * 3 + 2] = czA;
      scB[step * 3 + 0] = cxB; scB[step * 3 + 1] = cyB; scB[step * 3 + 2] = czB;
    }
  }
  __syncthreads();
  float* oA = out_xyz + (size_t)b0 * NPOINT * 3;
  float* oB = out_xyz + (size_t)b1 * NPOINT * 3;
  for (int i = t; i < NPOINT * 3; i += 256) { oA[i] = scA[i]; oB[i] = scB[i]; }
}

// one block per (batch b = blockIdx.x, center j = blockIdx.y), 256 threads.
// blockID % 8 == b % 8 -> each XCD's L2 serves exactly 2 batches.
__global__ __launch_bounds__(256) void center_kernel(
    const float* __restrict__ xyz, const float* __restrict__ featT,
    const float* __restrict__ W1, const float* __restrict__ b1,
    const float* __restrict__ W2, const float* __restrict__ b2,
    const float* __restrict__ Wcr, const float* __restrict__ bcr,
    const float* __restrict__ new_xyz, float* __restrict__ out_feat)
{
  int b = blockIdx.x, j = blockIdx.y, t = threadIdx.x;
  int wid = t >> 6, lane = t & 63;
  int quad = lane >> 4, col = lane & 15;
  __shared__ _Float16 sW2T[144][40];    // B operand: [channel n][k]
  __shared__ _Float16 sH1T[96][40];     // A operand: [sample m][k]
  __shared__ float sB2[144];
  __shared__ float sRel[96][4];
  __shared__ int   sIdx[96];
  __shared__ int   lI0[4][16], lI1[4][32], lI2[4][48];
  __shared__ int   lC[4][3];
  __shared__ float sPool[3][132];

  // ---- Phase A: coalesced W2 stage; each wave ball-queries a 512-pt range ----
  {
    bool act = t < 144;
    float v;
#pragma unroll 4
    for (int k = 0; k < 32; ++k) {
      v = (t < CIN) ? W2[k * CIN + t] : 0.f;   // consecutive t -> coalesced
      if (act) sW2T[t][k] = (_Float16)v;
    }
    if (t < 144) sB2[t] = (t < CIN) ? b2[t] : 0.f;
  }
  float cx = new_xyz[((size_t)b * NPOINT + j) * 3 + 0];
  float cy = new_xyz[((size_t)b * NPOINT + j) * 3 + 1];
  float cz = new_xyz[((size_t)b * NPOINT + j) * 3 + 2];
  {
    const float* xb = xyz + (size_t)b * NPTS * 3;
    unsigned long long lt = (1ull << lane) - 1ull;
    int c0 = 0, c1 = 0, c2 = 0;
    for (int it = 0; it < 8; ++it) {
      int n = (wid << 9) + (it << 6) + lane;
      float qx = xb[n * 3 + 0], qy = xb[n * 3 + 1], qz = xb[n * 3 + 2];
      float d2 = d2_rn(cx, cy, cz, qx, qy, qz);
      bool i0 = d2 < 0.01f, i1 = d2 < 0.04f, i2 = d2 < 0.16f;
      unsigned long long m0 = __ballot(i0), m1 = __ballot(i1), m2 = __ballot(i2);
      if (i0) { int p = c0 + __popcll(m0 & lt); if (p < 16) lI0[wid][p] = n; }
      if (i1) { int p = c1 + __popcll(m1 & lt); if (p < 32) lI1[wid][p] = n; }
      if (i2) { int p = c2 + __popcll(m2 & lt); if (p < 48) lI2[wid][p] = n; }
      c0 += __popcll(m0); c1 += __popcll(m1); c2 += __popcll(m2);
    }
    if (lane == 0) { lC[wid][0] = c0; lC[wid][1] = c1; lC[wid][2] = c2; }
  }
  __syncthreads();

  // ---- Phase B: merge ranges (exact first-k ascending) + h1 for own sample ----
  if (t < 96) {
    int rad = (t < 16) ? 0 : ((t < 48) ? 1 : 2);
    int g = t - ((rad == 0) ? 0 : ((rad == 1) ? 16 : 48));
    int q0 = lC[0][rad], q1 = lC[1][rad], q2 = lC[2][rad], q3 = lC[3][rad];
    const int* L0 = (rad == 0) ? lI0[0] : (rad == 1) ? lI1[0] : lI2[0];
    const int* L1 = (rad == 0) ? lI0[1] : (rad == 1) ? lI1[1] : lI2[1];
    const int* L2 = (rad == 0) ? lI0[2] : (rad == 1) ? lI1[2] : lI2[2];
    const int* L3 = (rad == 0) ? lI0[3] : (rad == 1) ? lI1[3] : lI2[3];
    int idx = -1, gg = g;
    if (gg < q0) idx = L0[gg]; else { gg -= q0;
    if (gg < q1) idx = L1[gg]; else { gg -= q1;
    if (gg < q2) idx = L2[gg]; else { gg -= q2;
    if (gg < q3) idx = L3[gg]; } } }
    if (idx < 0)   // pad with first in-ball index (center itself is in-ball)
      idx = (q0 > 0) ? L0[0] : (q1 > 0) ? L1[0] : (q2 > 0) ? L2[0] : L3[0];
    sIdx[t] = idx;

    const float* pp = xyz + ((size_t)b * NPTS + (size_t)idx) * 3;
    float ppx = pp[0], ppy = pp[1], ppz = pp[2];
    float rx = __fsub_rn(ppx, cx), ry = __fsub_rn(ppy, cy), rz = __fsub_rn(ppz, cz);
    float dist = sqrtf(__fadd_rn(__fadd_rn(__fmul_rn(rx, rx), __fmul_rn(ry, ry)),
                                 __fmul_rn(rz, rz)));
    sRel[t][0] = rx; sRel[t][1] = ry; sRel[t][2] = rz; sRel[t][3] = 0.f;
    float h10[10] = {dist, cx, cy, cz, ppx, ppy, ppz, rx, ry, rz};
    _Float16 h1h[CMID];
#pragma unroll
    for (int k = 0; k < CMID; ++k) {
      float a = b1[k];
#pragma unroll
      for (int i = 0; i < 10; ++i) a = fmaf(h10[i], W1[i * CMID + k], a);
      h1h[k] = (_Float16)fmaxf(a, 0.f);
    }
    uint4* dstv = (uint4*)&sH1T[t][0];
    const uint4* srcv = (const uint4*)h1h;
#pragma unroll
    for (int q = 0; q < 4; ++q) dstv[q] = srcv[q];
  }
  __syncthreads();

  // ---- Phase C: h2 via MFMA, relu(h2*x), segmented max-pool ----
  const float* ftb = featT + (size_t)b * NPTS * CFEAT;
#pragma unroll 1
  for (int nt = wid; nt < 9; nt += 4) {
    int c = (nt << 4) + col;
    half8 Bv = *(const half8*)&sW2T[c][quad << 3];   // fixed per n-tile
    float b2c = sB2[c];
    float sm0 = 0.f, sm1 = 0.f, sm2 = 0.f;
#pragma unroll
    for (int mt = 0; mt < 6; ++mt) {
      half8 A = *(const half8*)&sH1T[(mt << 4) + col][quad << 3];
      floatx4 acc = {0.f, 0.f, 0.f, 0.f};
      acc = __builtin_amdgcn_mfma_f32_16x16x32_f16(A, Bv, acc, 0, 0, 0);
#pragma unroll
      for (int r = 0; r < 4; ++r) {
        int sm = (mt << 4) + (quad << 2) + r;     // sample (D row)
        float x;
        if (c < 3)        x = sRel[sm][c];
        else if (c < CIN) x = ftb[(size_t)sIdx[sm] * CFEAT + (c - 3)];
        else              x = 0.f;
        float h2 = __fadd_rn(acc[r], b2c);
        float v = fmaxf(__fmul_rn(h2, x), 0.f);
        if (mt == 0)      sm0 = fmaxf(sm0, v);
        else if (mt < 3)  sm1 = fmaxf(sm1, v);
        else              sm2 = fmaxf(sm2, v);
      }
    }
    // combine the 4 quads (same channel, different samples): 2 shfls per segment
    sm0 = fmaxf(sm0, __shfl_xor(sm0, 16)); sm0 = fmaxf(sm0, __shfl_xor(sm0, 32));
    sm1 = fmaxf(sm1, __shfl_xor(sm1, 16)); sm1 = fmaxf(sm1, __shfl_xor(sm1, 32));
    sm2 = fmaxf(sm2, __shfl_xor(sm2, 16)); sm2 = fmaxf(sm2, __shfl_xor(sm2, 32));
    if (quad == 0 && c < CIN) {
      sPool[0][c] = sm0; sPool[1][c] = sm1; sPool[2][c] = sm2;
    }
  }
  __syncthreads();

  // ---- Phase D: out = relu(pooled @ Wcr + bcr), ALL 256 threads active ----
  {
    float* ob = out_feat + (size_t)b * 384 * NPOINT + j;
#pragma unroll 1
    for (int o = t; o < 384; o += 256) {
      int rad = o >> 7, c = o & 127;
      const float* pool = sPool[rad];
      float s = bcr[c];
#pragma unroll 4
      for (int k = 0; k < CIN; ++k) s = fmaf(pool[k], Wcr[k * CFEAT + c], s);
      ob[(size_t)o * NPOINT] = fmaxf(s, 0.f);
    }
  }
}

extern "C" void kernel_launch(void* const* d_in, const int* in_sizes, int n_in,
                              void* d_out, int out_size, void* d_ws, size_t ws_size,
                              hipStream_t stream) {
  const float* xyz  = (const float*)d_in[0];
  const float* feat = (const float*)d_in[1];
  const float* W1   = (const float*)d_in[2];
  const float* b1   = (const float*)d_in[3];
  const float* W2   = (const float*)d_in[4];
  const float* b2   = (const float*)d_in[5];
  const float* Wcr  = (const float*)d_in[6];
  const float* bcr  = (const float*)d_in[7];
  float* out_xyz  = (float*)d_out;                          // (B, 512, 3)
  float* out_feat = out_xyz + (size_t)BATCH * NPOINT * 3;   // (B, 384, 512)
  float* featT    = (float*)d_ws;                           // (B, N, C) 16 MB

  fps_transpose_kernel<<<NFPSBLK + BATCH * 256, 256, 0, stream>>>(xyz, feat, featT, out_xyz);
  // b on blockIdx.x: blockID % 8 == b % 8 -> XCD-local featT/xyz (L2-resident)
  center_kernel<<<dim3(BATCH, NPOINT), 256, 0, stream>>>(
      xyz, featT, W1, b1, W2, b2, Wcr, bcr, (const float*)d_out, out_feat);
}

// Round 7
// 564.330 us; speedup vs baseline: 1.4827x; 1.4827x over previous
//
#include <hip/hip_runtime.h>
#include <hip/hip_bf16.h>

#define BATCH   16
#define NPTS    2048
#define NPOINT  512
#define CFEAT   128
#define CIN     131
#define CMID    32

typedef _Float16 half8 __attribute__((ext_vector_type(8)));
typedef float floatx4 __attribute__((ext_vector_type(4)));

// exact (non-contracted) squared distance, matching np's ((dx^2+dy^2)+dz^2)
__device__ __forceinline__ float d2_rn(float ax, float ay, float az,
                                       float bx, float by, float bz) {
  float dx = __fsub_rn(ax, bx), dy = __fsub_rn(ay, by), dz = __fsub_rn(az, bz);
  return __fadd_rn(__fadd_rn(__fmul_rn(dx, dx), __fmul_rn(dy, dy)), __fmul_rn(dz, dz));
}

// 64-lane lexicographic max of (hi,lo), result lands in lane 63.
__device__ __forceinline__ void wave_key_reduce(unsigned &hi, unsigned &lo) {
#define KSTEP(CTRL, RM, BM) {                                                     \
    unsigned h2 = (unsigned)__builtin_amdgcn_update_dpp((int)hi, (int)hi, CTRL,   \
                                                        RM, BM, false);           \
    unsigned l2 = (unsigned)__builtin_amdgcn_update_dpp((int)lo, (int)lo, CTRL,   \
                                                        RM, BM, false);           \
    bool g = (h2 > hi) || (h2 == hi && l2 > lo);                                  \
    hi = g ? h2 : hi; lo = g ? l2 : lo; }
  KSTEP(0x111, 0xf, 0xf)   // row_shr:1
  KSTEP(0x112, 0xf, 0xf)   // row_shr:2
  KSTEP(0x114, 0xf, 0xe)   // row_shr:4
  KSTEP(0x118, 0xf, 0xc)   // row_shr:8
  KSTEP(0x142, 0xa, 0xf)   // row_bcast:15
  KSTEP(0x143, 0xc, 0xf)   // row_bcast:31
#undef KSTEP
}

// blocks [0,16): FPS per batch (R4 proven structure); blocks [16,16+4096): transpose
__global__ __launch_bounds__(256, 1) void fps_transpose_kernel(
    const float* __restrict__ xyz, const float* __restrict__ feat,
    float* __restrict__ featT, float* __restrict__ out_xyz)
{
  int t = threadIdx.x;
  if (blockIdx.x >= BATCH) {
    __shared__ float tile[32][33];
    int m  = blockIdx.x - BATCH;
    int b  = m >> 8;
    int c0 = ((m >> 6) & 3) << 5;
    int n0 = (m & 63) << 5;
    int tx = t & 31, ty = t >> 5;
    const float* src = feat  + (size_t)b * CFEAT * NPTS;
    float*       dst = featT + (size_t)b * NPTS * CFEAT;
#pragma unroll
    for (int i = 0; i < 4; ++i)
      tile[ty + 8 * i][tx] = src[(size_t)(c0 + ty + 8 * i) * NPTS + n0 + tx];
    __syncthreads();
#pragma unroll
    for (int i = 0; i < 4; ++i)
      dst[(size_t)(n0 + ty + 8 * i) * CFEAT + c0 + tx] = tile[tx][ty + 8 * i];
    return;
  }
  // ---- FPS: one block per batch, 256 threads, 8 pts/thread in registers ----
  __shared__ float4 sp[NPTS];                 // 32 KB (winner-coord source)
  __shared__ unsigned long long skey[2][4];
  __shared__ float scoord[NPOINT * 3];        // 6 KB: no global ops in the loop
  int b = blockIdx.x, lane = t & 63, wid = t >> 6;
  const float* xb = xyz + (size_t)b * NPTS * 3;
  for (int n = t; n < NPTS; n += 256) {
    const float* p = xb + n * 3;
    sp[n] = make_float4(p[0], p[1], p[2], 0.f);
  }
  __syncthreads();
  float px[8], py[8], pz[8], d[8];
#pragma unroll
  for (int i = 0; i < 8; ++i) {
    float4 q = sp[(i << 8) + t];
    px[i] = q.x; py[i] = q.y; pz[i] = q.z;
    d[i] = 1e10f;
  }
  float cx, cy, cz;
  { float4 q = sp[0]; cx = q.x; cy = q.y; cz = q.z; }
  if (t == 0) { scoord[0] = cx; scoord[1] = cy; scoord[2] = cz; }
#pragma unroll 1
  for (int step = 1; step < NPOINT; ++step) {
    unsigned long long bk = 0ull;
#pragma unroll
    for (int i = 0; i < 8; ++i) {
      float dd = d2_rn(px[i], py[i], pz[i], cx, cy, cz);
      float nd = fminf(d[i], dd);
      d[i] = nd;
      // key = dist_bits : ~n  (bigger ~n == smaller n -> argmax first-occurrence)
      unsigned long long key = ((unsigned long long)__float_as_uint(nd) << 32)
                             | (unsigned)~((i << 8) + t);
      bk = key > bk ? key : bk;
    }
    unsigned khi = (unsigned)(bk >> 32), klo = (unsigned)bk;
    wave_key_reduce(khi, klo);
    int p = step & 1;   // double-buffered -> one barrier per step
    if (lane == 63)
      skey[p][wid] = ((unsigned long long)khi << 32) | (unsigned long long)klo;
    __syncthreads();
    unsigned long long k0 = skey[p][0], k1 = skey[p][1];
    unsigned long long k2 = skey[p][2], k3 = skey[p][3];
    unsigned long long ka = k0 > k1 ? k0 : k1;
    unsigned long long kb = k2 > k3 ? k2 : k3;
    unsigned long long km = ka > kb ? ka : kb;
    int last = (int)(~(unsigned)(km & 0xFFFFFFFFull)) & (NPTS - 1);
    float4 q = sp[last];            // broadcast read
    cx = q.x; cy = q.y; cz = q.z;
    if (t == 0) {
      scoord[step * 3 + 0] = cx; scoord[step * 3 + 1] = cy; scoord[step * 3 + 2] = cz;
    }
  }
  __syncthreads();
  float* ob = out_xyz + (size_t)b * NPOINT * 3;
  for (int i = t; i < NPOINT * 3; i += 256) ob[i] = scoord[i];
}

// one block per (batch b = blockIdx.x, center j = blockIdx.y), 128 threads (2 waves).
// blockID % 8 == b % 8 -> each XCD's L2 serves exactly 2 batches.
__global__ __launch_bounds__(128) void center_kernel(
    const float* __restrict__ xyz, const float* __restrict__ featT,
    const float* __restrict__ W1, const float* __restrict__ b1,
    const float* __restrict__ W2, const float* __restrict__ b2,
    const float* __restrict__ Wcr, const float* __restrict__ bcr,
    const float* __restrict__ new_xyz, float* __restrict__ out_feat)
{
  int b = blockIdx.x, j = blockIdx.y, t = threadIdx.x;
  int wid = t >> 6, lane = t & 63;
  int quad = lane >> 4, col = lane & 15;
  __shared__ _Float16 sW2T[144][40];    // B operand: [channel n][k]
  __shared__ _Float16 sH1T[96][40];     // A operand: [sample m][k]
  __shared__ float sB2[144];
  __shared__ float sRel[96][4];
  __shared__ int   sIdx[96];
  __shared__ int   lI0[4][16], lI1[4][32], lI2[4][48];
  __shared__ int   lC[4][3];
  __shared__ float sPool[3][132];

  // ---- Phase A: coalesced W2 stage; each wave ball-queries TWO 512-pt ranges ----
  for (int c = t; c < 144; c += 128) {
    bool in = c < CIN;
#pragma unroll 4
    for (int k = 0; k < 32; ++k)
      sW2T[c][k] = (_Float16)(in ? W2[k * CIN + c] : 0.f);
    sB2[c] = in ? b2[c] : 0.f;
  }
  float cx = new_xyz[((size_t)b * NPOINT + j) * 3 + 0];
  float cy = new_xyz[((size_t)b * NPOINT + j) * 3 + 1];
  float cz = new_xyz[((size_t)b * NPOINT + j) * 3 + 2];
  {
    const float* xb = xyz + (size_t)b * NPTS * 3;
    unsigned long long lt = (1ull << lane) - 1ull;
#pragma unroll 1
    for (int half = 0; half < 2; ++half) {
      int rng = (wid << 1) + half;          // ranges 0..3, ascending n within each
      int c0 = 0, c1 = 0, c2 = 0;
#pragma unroll 1
      for (int it = 0; it < 8; ++it) {
        int n = (rng << 9) + (it << 6) + lane;
        float qx = xb[n * 3 + 0], qy = xb[n * 3 + 1], qz = xb[n * 3 + 2];
        float d2 = d2_rn(cx, cy, cz, qx, qy, qz);
        bool i0 = d2 < 0.01f, i1 = d2 < 0.04f, i2 = d2 < 0.16f;
        unsigned long long m0 = __ballot(i0), m1 = __ballot(i1), m2 = __ballot(i2);
        if (i0) { int p = c0 + __popcll(m0 & lt); if (p < 16) lI0[rng][p] = n; }
        if (i1) { int p = c1 + __popcll(m1 & lt); if (p < 32) lI1[rng][p] = n; }
        if (i2) { int p = c2 + __popcll(m2 & lt); if (p < 48) lI2[rng][p] = n; }
        c0 += __popcll(m0); c1 += __popcll(m1); c2 += __popcll(m2);
      }
      if (lane == 0) { lC[rng][0] = c0; lC[rng][1] = c1; lC[rng][2] = c2; }
    }
  }
  __syncthreads();

  // ---- Phase B: merge ranges (exact first-k ascending) + h1 for own sample ----
  if (t < 96) {
    int rad = (t < 16) ? 0 : ((t < 48) ? 1 : 2);
    int g = t - ((rad == 0) ? 0 : ((rad == 1) ? 16 : 48));
    int q0 = lC[0][rad], q1 = lC[1][rad], q2 = lC[2][rad], q3 = lC[3][rad];
    const int* L0 = (rad == 0) ? lI0[0] : (rad == 1) ? lI1[0] : lI2[0];
    const int* L1 = (rad == 0) ? lI0[1] : (rad == 1) ? lI1[1] : lI2[1];
    const int* L2 = (rad == 0) ? lI0[2] : (rad == 1) ? lI1[2] : lI2[2];
    const int* L3 = (rad == 0) ? lI0[3] : (rad == 1) ? lI1[3] : lI2[3];
    int idx = -1, gg = g;
    if (gg < q0) idx = L0[gg]; else { gg -= q0;
    if (gg < q1) idx = L1[gg]; else { gg -= q1;
    if (gg < q2) idx = L2[gg]; else { gg -= q2;
    if (gg < q3) idx = L3[gg]; } } }
    if (idx < 0)   // pad with first in-ball index (center itself is in-ball)
      idx = (q0 > 0) ? L0[0] : (q1 > 0) ? L1[0] : (q2 > 0) ? L2[0] : L3[0];
    sIdx[t] = idx;

    const float* pp = xyz + ((size_t)b * NPTS + (size_t)idx) * 3;
    float ppx = pp[0], ppy = pp[1], ppz = pp[2];
    float rx = __fsub_rn(ppx, cx), ry = __fsub_rn(ppy, cy), rz = __fsub_rn(ppz, cz);
    float dist = sqrtf(__fadd_rn(__fadd_rn(__fmul_rn(rx, rx), __fmul_rn(ry, ry)),
                                 __fmul_rn(rz, rz)));
    sRel[t][0] = rx; sRel[t][1] = ry; sRel[t][2] = rz; sRel[t][3] = 0.f;
    float h10[10] = {dist, cx, cy, cz, ppx, ppy, ppz, rx, ry, rz};
    _Float16 h1h[CMID];
#pragma unroll
    for (int k = 0; k < CMID; ++k) {
      float a = b1[k];
#pragma unroll
      for (int i = 0; i < 10; ++i) a = fmaf(h10[i], W1[i * CMID + k], a);
      h1h[k] = (_Float16)fmaxf(a, 0.f);
    }
    uint4* dstv = (uint4*)&sH1T[t][0];
    const uint4* srcv = (const uint4*)h1h;
#pragma unroll
    for (int q = 0; q < 4; ++q) dstv[q] = srcv[q];
  }
  __syncthreads();

  // ---- Phase C: h2 via MFMA, relu(h2*x), segmented max-pool ----
  const float* ftb = featT + (size_t)b * NPTS * CFEAT;
  for (int nt = wid; nt < 9; nt += 2) {
    int c = (nt << 4) + col;
    half8 Bv = *(const half8*)&sW2T[c][quad << 3];   // fixed per n-tile
    float b2c = sB2[c];
    float sm0 = 0.f, sm1 = 0.f, sm2 = 0.f;
#pragma unroll
    for (int mt = 0; mt < 6; ++mt) {
      half8 A = *(const half8*)&sH1T[(mt << 4) + col][quad << 3];
      floatx4 acc = {0.f, 0.f, 0.f, 0.f};
      acc = __builtin_amdgcn_mfma_f32_16x16x32_f16(A, Bv, acc, 0, 0, 0);
#pragma unroll
      for (int r = 0; r < 4; ++r) {
        int sm = (mt << 4) + (quad << 2) + r;     // sample (D row)
        float x;
        if (c < 3)        x = sRel[sm][c];
        else if (c < CIN) x = ftb[(size_t)sIdx[sm] * CFEAT + (c - 3)];
        else              x = 0.f;
        float h2 = __fadd_rn(acc[r], b2c);
        float v = fmaxf(__fmul_rn(h2, x), 0.f);
        if (mt == 0)      sm0 = fmaxf(sm0, v);
        else if (mt < 3)  sm1 = fmaxf(sm1, v);
        else              sm2 = fmaxf(sm2, v);
      }
    }
    // combine the 4 quads (same channel, different samples): 2 shfls per segment
    sm0 = fmaxf(sm0, __shfl_xor(sm0, 16)); sm0 = fmaxf(sm0, __shfl_xor(sm0, 32));
    sm1 = fmaxf(sm1, __shfl_xor(sm1, 16)); sm1 = fmaxf(sm1, __shfl_xor(sm1, 32));
    sm2 = fmaxf(sm2, __shfl_xor(sm2, 16)); sm2 = fmaxf(sm2, __shfl_xor(sm2, 32));
    if (quad == 0 && c < CIN) {
      sPool[0][c] = sm0; sPool[1][c] = sm1; sPool[2][c] = sm2;
    }
  }
  __syncthreads();

  // ---- Phase D: out = relu(pooled @ Wcr + bcr), 3 radii/thread (Wcr reuse) ----
  {
    float s0 = bcr[t], s1 = s0, s2 = s0;
#pragma unroll 4
    for (int k = 0; k < CIN; ++k) {
      float w = Wcr[k * CFEAT + t];
      s0 = fmaf(sPool[0][k], w, s0);
      s1 = fmaf(sPool[1][k], w, s1);
      s2 = fmaf(sPool[2][k], w, s2);
    }
    float* ob = out_feat + (size_t)b * 384 * NPOINT + j;
    ob[(size_t)(0 * CFEAT + t) * NPOINT] = fmaxf(s0, 0.f);
    ob[(size_t)(1 * CFEAT + t) * NPOINT] = fmaxf(s1, 0.f);
    ob[(size_t)(2 * CFEAT + t) * NPOINT] = fmaxf(s2, 0.f);
  }
}

extern "C" void kernel_launch(void* const* d_in, const int* in_sizes, int n_in,
                              void* d_out, int out_size, void* d_ws, size_t ws_size,
                              hipStream_t stream) {
  const float* xyz  = (const float*)d_in[0];
  const float* feat = (const float*)d_in[1];
  const float* W1   = (const float*)d_in[2];
  const float* b1   = (const float*)d_in[3];
  const float* W2   = (const float*)d_in[4];
  const float* b2   = (const float*)d_in[5];
  const float* Wcr  = (const float*)d_in[6];
  const float* bcr  = (const float*)d_in[7];
  float* out_xyz  = (float*)d_out;                          // (B, 512, 3)
  float* out_feat = out_xyz + (size_t)BATCH * NPOINT * 3;   // (B, 384, 512)
  float* featT    = (float*)d_ws;                           // (B, N, C) 16 MB

  fps_transpose_kernel<<<BATCH + BATCH * 256, 256, 0, stream>>>(xyz, feat, featT, out_xyz);
  // b on blockIdx.x: blockID % 8 == b % 8 -> XCD-local featT/xyz (L2-resident)
  center_kernel<<<dim3(BATCH, NPOINT), 128, 0, stream>>>(
      xyz, featT, W1, b1, W2, b2, Wcr, bcr, (const float*)d_out, out_feat);
}